// Round 4
// baseline (4578.186 us; speedup 1.0000x reference)
//
#include <hip/hip_runtime.h>
#include <hip/hip_bf16.h>
#include <stdint.h>

// ---------------------------------------------------------------------------
// NaiveLSTM: B=64, T=1024, I=512, H=512
//   phase 0: convert x->bf16; transpose W,U; init hist (slot0=0, rest=NaN
//            sentinel) + zero claim slots
//   phase 1: xW = x @ W  (bf16 MFMA GEMM, global_load_lds staging)
//   phase 2: sequential LSTM. 4 groups x 16 rows x 16 blocks. 256 blocks
//            launched; each block reads its physical XCC_ID (s_getreg) and
//            CAS-claims a slot in group = XCD (XCDs 0-3), so each group is
//            same-XCD BY CONSTRUCTION -> h exchange: producer sc1 store
//            (write-through, updates shared XCD L2 + LLC), consumer sc0 poll
//            (L2 hit ~200cyc). Sticky sc1 fallback keeps any placement
//            correct. Losers of the claim exit immediately.
// ---------------------------------------------------------------------------

typedef __attribute__((ext_vector_type(8))) short bf16x8;
typedef __attribute__((ext_vector_type(4))) float f32x4;

constexpr int T_STEPS = 1024;
constexpr int HS = 512;
constexpr int NGROUP = 4;                        // batch groups, 16 rows each
constexpr unsigned SENT = 0x7FC07FC0u;           // bf16 NaN pair
constexpr int HIST_SLOT_U32 = 16 * 512 / 2;      // 4096 u32 = 16KB per step/group

__device__ __forceinline__ unsigned short f2bf(float f) {
  unsigned u = __float_as_uint(f);
  u += 0x7fffu + ((u >> 16) & 1u);               // RNE
  return (unsigned short)(u >> 16);
}
__device__ __forceinline__ float bf_lo(unsigned u) { return __uint_as_float(u << 16); }
__device__ __forceinline__ float bf_hi(unsigned u) { return __uint_as_float(u & 0xffff0000u); }

__device__ __forceinline__ float fast_sig(float x) {
  return __builtin_amdgcn_rcpf(1.f + __expf(-x));
}
__device__ __forceinline__ float fast_tanh(float x) {
  return 2.f * __builtin_amdgcn_rcpf(1.f + __expf(-2.f * x)) - 1.f;
}

// ----- system-scope (LLC, cross-XCD safe) ops -----
__device__ __forceinline__ void stg_u32_llc(void* p, unsigned v) {
  asm volatile("global_store_dword %0, %1, off sc0 sc1" :: "v"(p), "v"(v) : "memory");
}
__device__ __forceinline__ void ldg_64B_llc(const void* p, uint4& a, uint4& b, uint4& c, uint4& d) {
  const char* q = (const char*)p;
  asm volatile(
      "global_load_dwordx4 %0, %4, off sc0 sc1\n\t"
      "global_load_dwordx4 %1, %5, off sc0 sc1\n\t"
      "global_load_dwordx4 %2, %6, off sc0 sc1\n\t"
      "global_load_dwordx4 %3, %7, off sc0 sc1\n\t"
      "s_waitcnt vmcnt(0)"
      : "=&v"(a), "=&v"(b), "=&v"(c), "=&v"(d)
      : "v"(q), "v"(q + 16), "v"(q + 32), "v"(q + 48)
      : "memory");
}
// ----- agent-scope (shared XCD L2) poll: valid when producer+consumer same XCD -----
__device__ __forceinline__ void ldg_64B_l2(const void* p, uint4& a, uint4& b, uint4& c, uint4& d) {
  const char* q = (const char*)p;
  asm volatile(
      "global_load_dwordx4 %0, %4, off sc0\n\t"
      "global_load_dwordx4 %1, %5, off sc0\n\t"
      "global_load_dwordx4 %2, %6, off sc0\n\t"
      "global_load_dwordx4 %3, %7, off sc0\n\t"
      "s_waitcnt vmcnt(0)"
      : "=&v"(a), "=&v"(b), "=&v"(c), "=&v"(d)
      : "v"(q), "v"(q + 16), "v"(q + 32), "v"(q + 48)
      : "memory");
}

// ---------------------------------------------------------------------------
__global__ __launch_bounds__(256) void conv_f32_to_bf16(const float* __restrict__ in,
                                                        uint4* __restrict__ out, int n16) {
  int i = blockIdx.x * 256 + threadIdx.x;
  const int stride = gridDim.x * 256;
  for (; i < n16; i += stride) {
    float4 a = ((const float4*)in)[2 * i];
    float4 b = ((const float4*)in)[2 * i + 1];
    uint4 o;
    o.x = (unsigned)f2bf(a.x) | ((unsigned)f2bf(a.y) << 16);
    o.y = (unsigned)f2bf(a.z) | ((unsigned)f2bf(a.w) << 16);
    o.z = (unsigned)f2bf(b.x) | ((unsigned)f2bf(b.y) << 16);
    o.w = (unsigned)f2bf(b.z) | ((unsigned)f2bf(b.w) << 16);
    out[i] = o;
  }
}

// ---------------------------------------------------------------------------
__global__ __launch_bounds__(256) void transpose_to_bf16(const float* __restrict__ in,
                                                         unsigned short* __restrict__ out,
                                                         int R, int C) {
  __shared__ unsigned short tile[64][72];
  const int tx = threadIdx.x & 63, ty = threadIdx.x >> 6;
  const int c0 = blockIdx.x * 64, r0 = blockIdx.y * 64;
#pragma unroll
  for (int rr = ty; rr < 64; rr += 4)
    tile[rr][tx] = f2bf(in[(size_t)(r0 + rr) * C + c0 + tx]);
  __syncthreads();
#pragma unroll
  for (int cc = ty; cc < 64; cc += 4)
    out[(size_t)(c0 + cc) * R + r0 + tx] = tile[tx][cc];
}

// ---------------------------------------------------------------------------
// hist init: per group, slot 0 (h0) = 0.0, slots 1..1024 = sentinel; also
// zeros the claim region. Runs EVERY launch (graph replays reuse buffers).
// ---------------------------------------------------------------------------
__global__ __launch_bounds__(256) void init_hist(uint4* __restrict__ hist4,
                                                 unsigned* __restrict__ claim) {
  const unsigned per_g = 1025u * 1024u;          // uint4 per group region (16KB slots)
  const unsigned total = NGROUP * per_g;
  unsigned i = blockIdx.x * 256 + threadIdx.x;
  if (i < 128) claim[i] = 0;                     // 64 slots + 4 counters + pad
  const unsigned stride = gridDim.x * 256;
  for (; i < total; i += stride) {
    const unsigned w = i % per_g;
    const unsigned v = (w < 1024u) ? 0u : SENT;  // slot 0 = 1024 uint4
    hist4[i] = make_uint4(v, v, v, v);
  }
}

// ---------------------------------------------------------------------------
// Phase 1 GEMM (unchanged): 128x128 tile, BK=64, global_load_lds staging.
// ---------------------------------------------------------------------------
__global__ __launch_bounds__(256, 1) void gemm_xw(const unsigned short* __restrict__ A,
                                                  const unsigned short* __restrict__ Bt,
                                                  unsigned short* __restrict__ C) {
  __shared__ __align__(16) char Al[128 * 128];
  __shared__ __align__(16) char Bl[128 * 128];
  const int tid = threadIdx.x, lane = tid & 63, wave = tid >> 6;
  const int n0 = blockIdx.x * 128;
  const size_t m0 = (size_t)blockIdx.y * 128;
  const int wm = wave >> 1, wn = wave & 1;
  f32x4 acc[4][4] = {};

  for (int ks = 0; ks < 8; ++ks) {
    const int k0 = ks * 64;
    if (ks) __syncthreads();
#pragma unroll
    for (int p = 0; p < 4; ++p) {
      const int off = p * 4096 + wave * 1024 + lane * 16;
      const int row = off >> 7, kb = off & 127;
      const unsigned short* ga = A + (m0 + row) * 512 + k0 + (kb >> 1);
      const unsigned short* gb = Bt + (size_t)(n0 + row) * 512 + k0 + (kb >> 1);
      __builtin_amdgcn_global_load_lds(
          (const __attribute__((address_space(1))) void*)ga,
          (__attribute__((address_space(3))) void*)(Al + p * 4096 + wave * 1024), 16, 0, 0);
      __builtin_amdgcn_global_load_lds(
          (const __attribute__((address_space(1))) void*)gb,
          (__attribute__((address_space(3))) void*)(Bl + p * 4096 + wave * 1024), 16, 0, 0);
    }
    __syncthreads();
#pragma unroll
    for (int kk = 0; kk < 2; ++kk) {
      const int kb = (kk * 32 + (lane >> 4) * 8) * 2;
      bf16x8 av[4], bv[4];
#pragma unroll
      for (int i = 0; i < 4; ++i)
        av[i] = *(const bf16x8*)(Al + (wm * 64 + i * 16 + (lane & 15)) * 128 + kb);
#pragma unroll
      for (int j = 0; j < 4; ++j)
        bv[j] = *(const bf16x8*)(Bl + (wn * 64 + j * 16 + (lane & 15)) * 128 + kb);
#pragma unroll
      for (int i = 0; i < 4; ++i)
#pragma unroll
        for (int j = 0; j < 4; ++j)
          acc[i][j] = __builtin_amdgcn_mfma_f32_16x16x32_bf16(av[i], bv[j], acc[i][j], 0, 0, 0);
    }
  }
#pragma unroll
  for (int i = 0; i < 4; ++i)
#pragma unroll
    for (int j = 0; j < 4; ++j) {
      const int col = n0 + wn * 64 + j * 16 + (lane & 15);
#pragma unroll
      for (int r = 0; r < 4; ++r) {
        const int row = wm * 64 + i * 16 + (lane >> 4) * 4 + r;
        C[(m0 + row) * (size_t)2048 + col] = f2bf(acc[i][j][r]);
      }
    }
}

// ---------------------------------------------------------------------------
// Phase 2: sequential LSTM. 256 blocks launched, 64 claim slots.
// slot = g*16+bg: group g (rows g*16..g*16+16), bg owns h-cols [bg*32,+32).
// Preferred claim puts group g on XCD g -> same-XCD exchange (sc0 polls).
// U fragments in registers (wave = gate). Per step:
//   xW(t+1) prefetch (drains under poll) -> poll h_t (sc0, sticky sc1
//   fallback) -> stage LDS -> syncA -> MFMA (4 chains) -> gl -> syncB ->
//   elementwise -> publish sc1 -> fp32 out (lazy).
// ---------------------------------------------------------------------------
__global__ __launch_bounds__(256, 1) void lstm_seq(const unsigned* __restrict__ xW,       // bf16 pairs [65536][1024]
                                                   const unsigned short* __restrict__ Ut, // bf16 [2048][512]
                                                   const float* __restrict__ bias,        // [2048]
                                                   float* __restrict__ out,
                                                   unsigned* __restrict__ hist,
                                                   unsigned* __restrict__ claim) {
  __shared__ __align__(16) unsigned short hl[2][16 * 512];  // dbuf, 32KB
  __shared__ float gl[4][16][32];                            // gate tiles, 8KB
  __shared__ float cl[16][32];                               // cell state, 2KB
  __shared__ int s_slot;

  const int tid = threadIdx.x, lane = tid & 63, wave = tid >> 6;

  // ---- claim a (group, bg) slot; prefer group = physical XCD ----
  if (tid == 0) {
    unsigned xcc = 0;
    asm volatile("s_getreg_b32 %0, hwreg(HW_REG_XCC_ID)" : "=s"(xcc));
    xcc &= 7u;
    int slot = -1;
    if (xcc < NGROUP) {
      unsigned c = atomicAdd(&claim[64 + xcc], 1u);
      if (c < 16u) {
        const int s = (int)(xcc * 16u + c);
        if (atomicCAS(&claim[s], 0u, 1u) == 0u) slot = s;
      }
    }
    if (slot < 0) {  // fallback: grab any unclaimed slot (any placement correct)
      for (int s = 0; s < 64; ++s)
        if (atomicCAS(&claim[s], 0u, 1u) == 0u) { slot = s; break; }
    }
    s_slot = slot;
  }
  __syncthreads();
  const int slot = s_slot;
  if (slot < 0) return;  // 192 losers exit
  const int g = slot >> 4;
  const int bg = slot & 15;
  const int c0 = bg * 32;
  const int bm0 = g * 16;

  // ---- one-time: U^T fragments into registers (wave = gate) ----
  bf16x8 uf[16][2];
#pragma unroll
  for (int ks = 0; ks < 16; ++ks)
#pragma unroll
    for (int j = 0; j < 2; ++j)
      uf[ks][j] = *(const bf16x8*)(Ut +
          (size_t)(wave * 512 + c0 + j * 16 + (lane & 15)) * 512 + ks * 32 + (lane >> 4) * 8);

  if (tid < 128) ((float4*)cl)[tid] = make_float4(0.f, 0.f, 0.f, 0.f);

  const int m = tid >> 4;          // batch row within group
  const int np = (tid & 15) * 2;   // col pair within block's 32 cols
  float bs[4][2];
#pragma unroll
  for (int gg = 0; gg < 4; ++gg) {
    bs[gg][0] = bias[gg * 512 + c0 + np];
    bs[gg][1] = bias[gg * 512 + c0 + np + 1];
  }

  const int am = lane & 15;
  const int asw = (am & 7) << 4;
  const int kgb = (lane >> 4) * 16;
  const int rowb = (tid >> 4) * 1024;
  const int colb = (tid & 15) * 64;
  const int sw = ((tid >> 4) & 7) << 4;

  // prologue xW prefetch for t=0
  unsigned xwv[4];
  {
    const unsigned* base = xW + (size_t)(bm0 + m) * T_STEPS * 1024;
#pragma unroll
    for (int gg = 0; gg < 4; ++gg) xwv[gg] = base[(gg * 512 + c0 + np) >> 1];
  }

  int llc_mode = 0;  // sticky: 0 = local-L2 poll, 1 = LLC poll
  __syncthreads();   // cl init visible

  for (int t = 0; t < T_STEPS; ++t) {
    // ---- prefetch NEXT step's xW at loop top: drains under the poll's
    //      vmcnt(0), never under a barrier (round-3 lesson) ----
    unsigned xwn[4];
    {
      const int tn = (t + 1 < T_STEPS) ? t + 1 : t;
      const unsigned* base = xW + ((size_t)(bm0 + m) * T_STEPS + tn) * 1024;
#pragma unroll
      for (int gg = 0; gg < 4; ++gg) xwn[gg] = base[(gg * 512 + c0 + np) >> 1];
    }
    // ---- poll h_t data (sc0 same-XCD fast path, sticky sc1 fallback) ----
    uint4 a, b, c, d;
    {
      const char* hb = (const char*)hist + (size_t)(g * 1025 + t) * 16384 + tid * 64;
      int tries = 0;
      for (;;) {
        if (llc_mode) ldg_64B_llc(hb, a, b, c, d);
        else          ldg_64B_l2(hb, a, b, c, d);
        const bool bad = (a.x == SENT) | (a.y == SENT) | (a.z == SENT) | (a.w == SENT) |
                         (b.x == SENT) | (b.y == SENT) | (b.z == SENT) | (b.w == SENT) |
                         (c.x == SENT) | (c.y == SENT) | (c.z == SENT) | (c.w == SENT) |
                         (d.x == SENT) | (d.y == SENT) | (d.z == SENT) | (d.w == SENT);
        if (!bad) break;
        if (!llc_mode && ++tries >= 256) llc_mode = 1;  // cross-XCD -> LLC forever
      }
    }
    // ---- stage h_t to LDS (swizzled) ----
    {
      char* dst = (char*)hl[t & 1];
      *(uint4*)(dst + ((rowb + colb) ^ sw)) = a;
      *(uint4*)(dst + ((rowb + colb + 16) ^ sw)) = b;
      *(uint4*)(dst + ((rowb + colb + 32) ^ sw)) = c;
      *(uint4*)(dst + ((rowb + colb + 48) ^ sw)) = d;
    }
    __syncthreads();  // sync A

    // ---- h_t @ U slice: wave = gate, 4 dep-chains of 8 ----
    f32x4 p0 = {0.f, 0.f, 0.f, 0.f}, p1 = p0, q0 = p0, q1 = p0;
    const char* hbase = (const char*)hl[t & 1];
#pragma unroll
    for (int ks = 0; ks < 16; ks += 2) {
      bf16x8 av0 = *(const bf16x8*)(hbase + ((am * 1024 + ks * 64 + kgb) ^ asw));
      bf16x8 av1 = *(const bf16x8*)(hbase + ((am * 1024 + (ks + 1) * 64 + kgb) ^ asw));
      p0 = __builtin_amdgcn_mfma_f32_16x16x32_bf16(av0, uf[ks][0], p0, 0, 0, 0);
      q0 = __builtin_amdgcn_mfma_f32_16x16x32_bf16(av0, uf[ks][1], q0, 0, 0, 0);
      p1 = __builtin_amdgcn_mfma_f32_16x16x32_bf16(av1, uf[ks + 1][0], p1, 0, 0, 0);
      q1 = __builtin_amdgcn_mfma_f32_16x16x32_bf16(av1, uf[ks + 1][1], q1, 0, 0, 0);
    }
    const f32x4 acc0 = p0 + p1, acc1 = q0 + q1;
    {
      const int col = lane & 15, row4 = (lane >> 4) * 4;
#pragma unroll
      for (int r = 0; r < 4; ++r) {
        gl[wave][row4 + r][col] = acc0[r];
        gl[wave][row4 + r][col + 16] = acc1[r];
      }
    }
    __syncthreads();  // sync B

    // ---- elementwise LSTM cell for this thread's (m, np..np+1) ----
    {
      float h0, h1, cA, cB;
      {
        const int nc = np;
        const float xi = gl[0][m][nc] + bf_lo(xwv[0]) + bs[0][0];
        const float xf = gl[1][m][nc] + bf_lo(xwv[1]) + bs[1][0];
        const float xg = gl[2][m][nc] + bf_lo(xwv[2]) + bs[2][0];
        const float xo = gl[3][m][nc] + bf_lo(xwv[3]) + bs[3][0];
        const float it = fast_sig(xi), ft = fast_sig(xf);
        const float gt = fast_tanh(xg), ot = fast_sig(xo);
        cA = ft * cl[m][nc] + it * gt;
        h0 = ot * fast_tanh(cA);
        cl[m][nc] = cA;
      }
      {
        const int nc = np + 1;
        const float xi = gl[0][m][nc] + bf_hi(xwv[0]) + bs[0][1];
        const float xf = gl[1][m][nc] + bf_hi(xwv[1]) + bs[1][1];
        const float xg = gl[2][m][nc] + bf_hi(xwv[2]) + bs[2][1];
        const float xo = gl[3][m][nc] + bf_hi(xwv[3]) + bs[3][1];
        const float it = fast_sig(xi), ft = fast_sig(xf);
        const float gt = fast_tanh(xg), ot = fast_sig(xo);
        cB = ft * cl[m][nc] + it * gt;
        h1 = ot * fast_tanh(cB);
        cl[m][nc] = cB;
      }
      // publish h_{t+1} FIRST (sc1 write-through: LLC + producer-XCD L2)
      const unsigned hp = (unsigned)f2bf(h0) | ((unsigned)f2bf(h1) << 16);
      stg_u32_llc(hist + (size_t)(g * 1025 + t + 1) * HIST_SLOT_U32 + m * 256 + ((c0 + np) >> 1), hp);
      // fp32 hidden_seq output (retires lazily under next step's poll)
      *(float2*)(out + ((size_t)(bm0 + m) * T_STEPS + t) * HS + c0 + np) = make_float2(h0, h1);
      if (t == T_STEPS - 1) {
        const size_t hs_total = (size_t)64 * T_STEPS * HS;
        *(float2*)(out + hs_total + (size_t)(bm0 + m) * HS + c0 + np) = make_float2(h0, h1);
        *(float2*)(out + hs_total + 64 * HS + (size_t)(bm0 + m) * HS + c0 + np) = make_float2(cA, cB);
      }
#pragma unroll
      for (int gg = 0; gg < 4; ++gg) xwv[gg] = xwn[gg];
    }
    // no end barrier: hl double-buffered; gl/cl rewrites fenced by sync A/B
  }
}

// ---------------------------------------------------------------------------
extern "C" void kernel_launch(void* const* d_in, const int* in_sizes, int n_in,
                              void* d_out, int out_size, void* d_ws, size_t ws_size,
                              hipStream_t stream) {
  const float* x = (const float*)d_in[0];
  const float* W = (const float*)d_in[1];
  const float* U = (const float*)d_in[2];
  const float* bias = (const float*)d_in[3];
  float* out = (float*)d_out;
  char* ws = (char*)d_ws;

  size_t off = 0;
  unsigned* claim = (unsigned*)(ws + off);            off += 4096;
  unsigned short* x_bf = (unsigned short*)(ws + off); off += (size_t)65536 * 512 * 2;        // 64MB
  unsigned short* Wt = (unsigned short*)(ws + off);   off += (size_t)2048 * 512 * 2;         // 2MB
  unsigned short* Ut = (unsigned short*)(ws + off);   off += (size_t)2048 * 512 * 2;         // 2MB
  unsigned* hist = (unsigned*)(ws + off);             off += (size_t)NGROUP * 1025 * 16384;  // 67MB
  unsigned short* xWb = (unsigned short*)(ws + off);  off += (size_t)65536 * 2048 * 2;       // 256MB
  if (ws_size < off) return;

  conv_f32_to_bf16<<<4096, 256, 0, stream>>>(x, (uint4*)x_bf, 33554432 / 8);
  transpose_to_bf16<<<dim3(32, 8), 256, 0, stream>>>(W, Wt, 512, 2048);
  transpose_to_bf16<<<dim3(32, 8), 256, 0, stream>>>(U, Ut, 512, 2048);
  init_hist<<<2048, 256, 0, stream>>>((uint4*)hist, claim);
  gemm_xw<<<dim3(16, 512), 256, 0, stream>>>(x_bf, Wt, xWb);
  lstm_seq<<<256, 256, 0, stream>>>((const unsigned*)xWb, Ut, bias, out, hist, claim);
}

// Round 7
// 3025.518 us; speedup vs baseline: 1.5132x; 1.5132x over previous
//
#include <hip/hip_runtime.h>
#include <hip/hip_bf16.h>
#include <stdint.h>

// ---------------------------------------------------------------------------
// NaiveLSTM: B=64, T=1024, I=512, H=512
//   phase 0: convert x->bf16; transpose W,U; init hist (slot0 = h0 = 0,
//            slots 1..1024 = bf16-NaN sentinel)
//   phase 1: xW = x @ W  (bf16 MFMA GEMM, global_load_lds staging)
//   phase 2: sequential LSTM, round-2 proven skeleton (64 blocks x 256 thr,
//            4 groups x 16 blocks, data-poll via sentinel, LDS h-stage,
//            ONE barrier/step) + lane-local gate layout:
//            mfma(A=U-frag with rows ordered (colpair,gate), B=h-frag) puts
//            all 4 gates of 2 adjacent cells in one lane -> no gate routing
//            through LDS, no second barrier, c-state in registers, publish
//            one u32, out one float2. U fragments pinned in 128 VGPRs.
// ---------------------------------------------------------------------------

typedef __attribute__((ext_vector_type(8))) short bf16x8;
typedef __attribute__((ext_vector_type(4))) float f32x4;

constexpr int T_STEPS = 1024;
constexpr int HS = 512;
constexpr int NGROUP = 4;                       // batch groups, 16 rows each
constexpr unsigned SENT = 0x7FC07FC0u;          // bf16 NaN pair; h finite always
constexpr int HIST_SLOT_U32 = 16 * 512 / 2;     // 4096 u32 = 16KB per step/group

__device__ __forceinline__ unsigned short f2bf(float f) {
  unsigned u = __float_as_uint(f);
  u += 0x7fffu + ((u >> 16) & 1u);              // RNE
  return (unsigned short)(u >> 16);
}
__device__ __forceinline__ float bf_lo(unsigned u) { return __uint_as_float(u << 16); }
__device__ __forceinline__ float bf_hi(unsigned u) { return __uint_as_float(u & 0xffff0000u); }

__device__ __forceinline__ float fast_sig(float x) {
  return __builtin_amdgcn_rcpf(1.f + __expf(-x));
}
__device__ __forceinline__ float fast_tanh(float x) {
  return 2.f * __builtin_amdgcn_rcpf(1.f + __expf(-2.f * x)) - 1.f;
}

// ----- system-scope (LLC, cross-XCD safe) ops — proven in rounds 1-4 -----
__device__ __forceinline__ void stg_u32_llc(void* p, unsigned v) {
  asm volatile("global_store_dword %0, %1, off sc0 sc1" :: "v"(p), "v"(v) : "memory");
}
__device__ __forceinline__ void ldg_64B_llc(const void* p, uint4& a, uint4& b, uint4& c, uint4& d) {
  const char* q = (const char*)p;
  asm volatile(
      "global_load_dwordx4 %0, %4, off sc0 sc1\n\t"
      "global_load_dwordx4 %1, %5, off sc0 sc1\n\t"
      "global_load_dwordx4 %2, %6, off sc0 sc1\n\t"
      "global_load_dwordx4 %3, %7, off sc0 sc1\n\t"
      "s_waitcnt vmcnt(0)"
      : "=&v"(a), "=&v"(b), "=&v"(c), "=&v"(d)
      : "v"(q), "v"(q + 16), "v"(q + 32), "v"(q + 48)
      : "memory");
}

// ---------------------------------------------------------------------------
__global__ __launch_bounds__(256) void conv_f32_to_bf16(const float* __restrict__ in,
                                                        uint4* __restrict__ out, int n16) {
  int i = blockIdx.x * 256 + threadIdx.x;
  const int stride = gridDim.x * 256;
  for (; i < n16; i += stride) {
    float4 a = ((const float4*)in)[2 * i];
    float4 b = ((const float4*)in)[2 * i + 1];
    uint4 o;
    o.x = (unsigned)f2bf(a.x) | ((unsigned)f2bf(a.y) << 16);
    o.y = (unsigned)f2bf(a.z) | ((unsigned)f2bf(a.w) << 16);
    o.z = (unsigned)f2bf(b.x) | ((unsigned)f2bf(b.y) << 16);
    o.w = (unsigned)f2bf(b.z) | ((unsigned)f2bf(b.w) << 16);
    out[i] = o;
  }
}

// ---------------------------------------------------------------------------
__global__ __launch_bounds__(256) void transpose_to_bf16(const float* __restrict__ in,
                                                         unsigned short* __restrict__ out,
                                                         int R, int C) {
  __shared__ unsigned short tile[64][72];
  const int tx = threadIdx.x & 63, ty = threadIdx.x >> 6;
  const int c0 = blockIdx.x * 64, r0 = blockIdx.y * 64;
#pragma unroll
  for (int rr = ty; rr < 64; rr += 4)
    tile[rr][tx] = f2bf(in[(size_t)(r0 + rr) * C + c0 + tx]);
  __syncthreads();
#pragma unroll
  for (int cc = ty; cc < 64; cc += 4)
    out[(size_t)(c0 + cc) * R + r0 + tx] = tile[tx][cc];
}

// ---------------------------------------------------------------------------
// hist init: per group, slot 0 (h0) = 0.0, slots 1..1024 = sentinel.
// Runs EVERY launch (graph replays reuse the buffer).
// ---------------------------------------------------------------------------
__global__ __launch_bounds__(256) void init_hist(uint4* __restrict__ hist4) {
  const unsigned per_g = 1025u * 1024u;          // uint4 per 16KB-slot group region
  const unsigned total = NGROUP * per_g;
  unsigned i = blockIdx.x * 256 + threadIdx.x;
  const unsigned stride = gridDim.x * 256;
  for (; i < total; i += stride) {
    const unsigned w = i % per_g;
    const unsigned v = (w < 1024u) ? 0u : SENT;  // slot 0 = 1024 uint4
    hist4[i] = make_uint4(v, v, v, v);
  }
}

// ---------------------------------------------------------------------------
// Phase 1 GEMM (unchanged, proven): 128x128 tile, BK=64, global_load_lds.
// ---------------------------------------------------------------------------
__global__ __launch_bounds__(256, 1) void gemm_xw(const unsigned short* __restrict__ A,
                                                  const unsigned short* __restrict__ Bt,
                                                  unsigned short* __restrict__ C) {
  __shared__ __align__(16) char Al[128 * 128];
  __shared__ __align__(16) char Bl[128 * 128];
  const int tid = threadIdx.x, lane = tid & 63, wave = tid >> 6;
  const int n0 = blockIdx.x * 128;
  const size_t m0 = (size_t)blockIdx.y * 128;
  const int wm = wave >> 1, wn = wave & 1;
  f32x4 acc[4][4] = {};

  for (int ks = 0; ks < 8; ++ks) {
    const int k0 = ks * 64;
    if (ks) __syncthreads();
#pragma unroll
    for (int p = 0; p < 4; ++p) {
      const int off = p * 4096 + wave * 1024 + lane * 16;
      const int row = off >> 7, kb = off & 127;
      const unsigned short* ga = A + (m0 + row) * 512 + k0 + (kb >> 1);
      const unsigned short* gb = Bt + (size_t)(n0 + row) * 512 + k0 + (kb >> 1);
      __builtin_amdgcn_global_load_lds(
          (const __attribute__((address_space(1))) void*)ga,
          (__attribute__((address_space(3))) void*)(Al + p * 4096 + wave * 1024), 16, 0, 0);
      __builtin_amdgcn_global_load_lds(
          (const __attribute__((address_space(1))) void*)gb,
          (__attribute__((address_space(3))) void*)(Bl + p * 4096 + wave * 1024), 16, 0, 0);
    }
    __syncthreads();
#pragma unroll
    for (int kk = 0; kk < 2; ++kk) {
      const int kb = (kk * 32 + (lane >> 4) * 8) * 2;
      bf16x8 av[4], bv[4];
#pragma unroll
      for (int i = 0; i < 4; ++i)
        av[i] = *(const bf16x8*)(Al + (wm * 64 + i * 16 + (lane & 15)) * 128 + kb);
#pragma unroll
      for (int j = 0; j < 4; ++j)
        bv[j] = *(const bf16x8*)(Bl + (wn * 64 + j * 16 + (lane & 15)) * 128 + kb);
#pragma unroll
      for (int i = 0; i < 4; ++i)
#pragma unroll
        for (int j = 0; j < 4; ++j)
          acc[i][j] = __builtin_amdgcn_mfma_f32_16x16x32_bf16(av[i], bv[j], acc[i][j], 0, 0, 0);
    }
  }
#pragma unroll
  for (int i = 0; i < 4; ++i)
#pragma unroll
    for (int j = 0; j < 4; ++j) {
      const int col = n0 + wn * 64 + j * 16 + (lane & 15);
#pragma unroll
      for (int r = 0; r < 4; ++r) {
        const int row = wm * 64 + i * 16 + (lane >> 4) * 4 + r;
        C[(m0 + row) * (size_t)2048 + col] = f2bf(acc[i][j][r]);
      }
    }
}

// ---------------------------------------------------------------------------
// Phase 2: sequential LSTM. 64 blocks x 256 threads (4 waves).
// group g = bid&3 (rows g*16..+16), bg = bid>>2 owns h-cols [bg*32, +32).
// Wave w owns 8 cols [C0, C0+8), C0 = bg*32 + w*8.
// MFMA: D = mfma(A=U-frag, B=h-frag). A rows r16 = (colpair = r16>>2,
// gate = r16&3); mfma1 covers cols C0+2*cp (even), mfma2 cols C0+2*cp+1.
// D: lane (b = lane&15, q = lane>>4) holds acc1[r] = gate r of (b, C0+2q)
// and acc2[r] = gate r of (b, C0+2q+1) -> elementwise/c-state/publish all
// lane-local. One barrier per step (stage -> read). U frags pinned in VGPRs.
// ---------------------------------------------------------------------------
__global__ __launch_bounds__(256, 1) void lstm_seq(const unsigned* __restrict__ xW,       // bf16 pairs [65536][1024]
                                                   const unsigned short* __restrict__ Ut, // bf16 [2048][512]
                                                   const float* __restrict__ bias,        // [2048]
                                                   float* __restrict__ out,
                                                   unsigned* __restrict__ hist) {
  __shared__ __align__(16) unsigned short hl[2][16 * 512];  // dbuf, 32KB

  const int tid = threadIdx.x, lane = tid & 63, wave = tid >> 6;
  const int g = blockIdx.x & 3;
  const int bg = blockIdx.x >> 2;
  const int C0 = bg * 32 + wave * 8;
  const int bm0 = g * 16;

  // A-side (U-frag load) roles
  const int r16 = lane & 15;            // A row within the 16
  const int gate_a = r16 & 3;           // gate of this A row
  const int cp_a = r16 >> 2;            // col-pair of this A row
  const int kq = lane >> 4;             // k-chunk id (8 elems within ks-slice)
  // D-side (output) roles
  const int b = lane & 15;              // batch row (in group)
  const int q = lane >> 4;              // col-pair id
  const int colA = C0 + 2 * q;          // output cols colA, colA+1
  const int bglob = bm0 + b;

  // ---- one-time: U fragments (2 mfma x 16 ks), pinned resident (128 VGPR) ----
  bf16x8 uf1[16], uf2[16];
  {
    const unsigned short* ua = Ut + (size_t)(gate_a * 512 + C0 + 2 * cp_a) * 512 + kq * 8;
#pragma unroll
    for (int ks = 0; ks < 16; ++ks) {
      uf1[ks] = *(const bf16x8*)(ua + ks * 32);
      uf2[ks] = *(const bf16x8*)(ua + 512 + ks * 32);   // col +1 -> one U row down
      asm volatile("" : "+v"(uf1[ks]));                 // pin: not rematerializable
      asm volatile("" : "+v"(uf2[ks]));
    }
  }

  float biasA[4], biasB[4];
#pragma unroll
  for (int r = 0; r < 4; ++r) {
    biasA[r] = bias[r * 512 + colA];
    biasB[r] = bias[r * 512 + colA + 1];
  }
  float cA = 0.f, cB = 0.f;             // cell state, lane-local

  // h B-frag read (from hl, round-2 swizzle): row = lane&15, k-chunk kq
  const int am = lane & 15;
  const int asw = (am & 7) << 4;
  const int kgb = kq * 16;
  // stage roles (thread tid stages 64B of row tid>>4)
  const int rowb = (tid >> 4) * 1024;
  const int colb = (tid & 15) * 64;
  const int sw = ((tid >> 4) & 7) << 4;

  __syncthreads();

  for (int t = 0; t < T_STEPS; ++t) {
    // ---- xW(t) loads at loop top: drain under the poll's vmcnt(0) ----
    unsigned xwv[4];
    {
      const unsigned* base = xW + (size_t)(bglob * T_STEPS + t) * 1024;
#pragma unroll
      for (int r = 0; r < 4; ++r) xwv[r] = base[r * 256 + (colA >> 1)];
    }
    // ---- poll h_t data (sentinel; single LLC round trip) ----
    uint4 pa, pb, pc, pd;
    {
      const char* hb = (const char*)hist + (size_t)(g * 1025 + t) * 16384 + tid * 64;
      for (;;) {
        ldg_64B_llc(hb, pa, pb, pc, pd);
        const bool bad = (pa.x == SENT) | (pa.y == SENT) | (pa.z == SENT) | (pa.w == SENT) |
                         (pb.x == SENT) | (pb.y == SENT) | (pb.z == SENT) | (pb.w == SENT) |
                         (pc.x == SENT) | (pc.y == SENT) | (pc.z == SENT) | (pc.w == SENT) |
                         (pd.x == SENT) | (pd.y == SENT) | (pd.z == SENT) | (pd.w == SENT);
        if (!bad) break;
      }
    }
    // ---- stage h_t to LDS (swizzled), double-buffered ----
    {
      char* dst = (char*)hl[t & 1];
      *(uint4*)(dst + ((rowb + colb) ^ sw)) = pa;
      *(uint4*)(dst + ((rowb + colb + 16) ^ sw)) = pb;
      *(uint4*)(dst + ((rowb + colb + 32) ^ sw)) = pc;
      *(uint4*)(dst + ((rowb + colb + 48) ^ sw)) = pd;
    }
    __syncthreads();  // the ONLY barrier per step

    // ---- acc init = bias + xW(t) ----
    f32x4 acc1, acc2;
#pragma unroll
    for (int r = 0; r < 4; ++r) {
      acc1[r] = biasA[r] + bf_lo(xwv[r]);
      acc2[r] = biasB[r] + bf_hi(xwv[r]);
    }
    // ---- 32 MFMA: 2 independent chains of 16 (h from LDS, U from VGPRs) ----
    const char* hbase = (const char*)hl[t & 1];
#pragma unroll
    for (int ks = 0; ks < 16; ++ks) {
      const bf16x8 hb8 = *(const bf16x8*)(hbase + ((am * 1024 + ks * 64 + kgb) ^ asw));
      acc1 = __builtin_amdgcn_mfma_f32_16x16x32_bf16(uf1[ks], hb8, acc1, 0, 0, 0);
      acc2 = __builtin_amdgcn_mfma_f32_16x16x32_bf16(uf2[ks], hb8, acc2, 0, 0, 0);
    }

    // ---- lane-local elementwise: 2 cells (b, colA), (b, colA+1) ----
    const float iA = fast_sig(acc1[0]), fA = fast_sig(acc1[1]);
    const float gA = fast_tanh(acc1[2]), oA = fast_sig(acc1[3]);
    cA = fA * cA + iA * gA;
    const float hA = oA * fast_tanh(cA);
    const float iB = fast_sig(acc2[0]), fB = fast_sig(acc2[1]);
    const float gB = fast_tanh(acc2[2]), oB = fast_sig(acc2[3]);
    cB = fB * cB + iB * gB;
    const float hB = oB * fast_tanh(cB);

    // ---- publish h_{t+1} FIRST (one u32, system scope) ----
    const unsigned hp = (unsigned)f2bf(hA) | ((unsigned)f2bf(hB) << 16);
    stg_u32_llc(hist + (size_t)(g * 1025 + t + 1) * HIST_SLOT_U32 + b * 256 + (colA >> 1), hp);
    // ---- fp32 hidden_seq (retires lazily under next poll) ----
    *(float2*)(out + ((size_t)bglob * T_STEPS + t) * HS + colA) = make_float2(hA, hB);
    if (t == T_STEPS - 1) {
      const size_t hs_total = (size_t)64 * T_STEPS * HS;
      *(float2*)(out + hs_total + (size_t)bglob * HS + colA) = make_float2(hA, hB);
      *(float2*)(out + hs_total + 64 * HS + (size_t)bglob * HS + colA) = make_float2(cA, cB);
    }
    // no second barrier: hl double-buffered; next overwrite of hl[t&1] is at
    // t+2's stage, gated by poll(t+2) <- publishes(t+1) <- all waves read hl[t&1]
  }
}

// ---------------------------------------------------------------------------
extern "C" void kernel_launch(void* const* d_in, const int* in_sizes, int n_in,
                              void* d_out, int out_size, void* d_ws, size_t ws_size,
                              hipStream_t stream) {
  const float* x = (const float*)d_in[0];
  const float* W = (const float*)d_in[1];
  const float* U = (const float*)d_in[2];
  const float* bias = (const float*)d_in[3];
  float* out = (float*)d_out;
  char* ws = (char*)d_ws;

  size_t off = 0;
  unsigned short* x_bf = (unsigned short*)(ws + off); off += (size_t)65536 * 512 * 2;        // 64MB
  unsigned short* Wt = (unsigned short*)(ws + off);   off += (size_t)2048 * 512 * 2;         // 2MB
  unsigned short* Ut = (unsigned short*)(ws + off);   off += (size_t)2048 * 512 * 2;         // 2MB
  unsigned* hist = (unsigned*)(ws + off);             off += (size_t)NGROUP * 1025 * 16384;  // 67MB
  unsigned short* xWb = (unsigned short*)(ws + off);  off += (size_t)65536 * 2048 * 2;       // 256MB
  if (ws_size < off) return;

  conv_f32_to_bf16<<<4096, 256, 0, stream>>>(x, (uint4*)x_bf, 33554432 / 8);
  transpose_to_bf16<<<dim3(32, 8), 256, 0, stream>>>(W, Wt, 512, 2048);
  transpose_to_bf16<<<dim3(32, 8), 256, 0, stream>>>(U, Ut, 512, 2048);
  init_hist<<<2048, 256, 0, stream>>>((uint4*)hist);
  gemm_xw<<<dim3(16, 512), 256, 0, stream>>>(x_bf, Wt, xWb);
  lstm_seq<<<64, 256, 0, stream>>>((const unsigned*)xWb, Ut, bias, out, hist);
}

// Round 8
// 3023.511 us; speedup vs baseline: 1.5142x; 1.0007x over previous
//
#include <hip/hip_runtime.h>
#include <hip/hip_bf16.h>
#include <stdint.h>

// ---------------------------------------------------------------------------
// NaiveLSTM: B=64, T=1024, I=512, H=512
//   phase 0: convert x->bf16; transpose W,U; init hist (slot0 = h0 = 0,
//            slots 1..1024 = bf16-NaN sentinel)
//   phase 1: xW = x @ W  (bf16 MFMA GEMM, global_load_lds staging)
//   phase 2: sequential LSTM, round-2 proven skeleton (64 blocks x 256 thr,
//            4 groups x 16 blocks, data-poll via sentinel, LDS h-stage,
//            ONE barrier/step) + lane-local gate layout:
//            mfma(A=U-frag with rows ordered (colpair,gate), B=h-frag) puts
//            all 4 gates of 2 adjacent cells in one lane -> no gate routing
//            through LDS, no second barrier, c-state in registers, publish
//            one u32, out one float2. U fragments pinned in 128 VGPRs.
// ---------------------------------------------------------------------------

typedef __attribute__((ext_vector_type(8))) short bf16x8;
typedef __attribute__((ext_vector_type(4))) float f32x4;

constexpr int T_STEPS = 1024;
constexpr int HS = 512;
constexpr int NGROUP = 4;                       // batch groups, 16 rows each
constexpr unsigned SENT = 0x7FC07FC0u;          // bf16 NaN pair; h finite always
constexpr int HIST_SLOT_U32 = 16 * 512 / 2;     // 4096 u32 = 16KB per step/group

__device__ __forceinline__ unsigned short f2bf(float f) {
  unsigned u = __float_as_uint(f);
  u += 0x7fffu + ((u >> 16) & 1u);              // RNE
  return (unsigned short)(u >> 16);
}
__device__ __forceinline__ float bf_lo(unsigned u) { return __uint_as_float(u << 16); }
__device__ __forceinline__ float bf_hi(unsigned u) { return __uint_as_float(u & 0xffff0000u); }

__device__ __forceinline__ float fast_sig(float x) {
  return __builtin_amdgcn_rcpf(1.f + __expf(-x));
}
__device__ __forceinline__ float fast_tanh(float x) {
  return 2.f * __builtin_amdgcn_rcpf(1.f + __expf(-2.f * x)) - 1.f;
}

// ----- system-scope (LLC, cross-XCD safe) ops — proven in rounds 1-4 -----
__device__ __forceinline__ void stg_u32_llc(void* p, unsigned v) {
  asm volatile("global_store_dword %0, %1, off sc0 sc1" :: "v"(p), "v"(v) : "memory");
}
__device__ __forceinline__ void ldg_64B_llc(const void* p, uint4& a, uint4& b, uint4& c, uint4& d) {
  const char* q = (const char*)p;
  asm volatile(
      "global_load_dwordx4 %0, %4, off sc0 sc1\n\t"
      "global_load_dwordx4 %1, %5, off sc0 sc1\n\t"
      "global_load_dwordx4 %2, %6, off sc0 sc1\n\t"
      "global_load_dwordx4 %3, %7, off sc0 sc1\n\t"
      "s_waitcnt vmcnt(0)"
      : "=&v"(a), "=&v"(b), "=&v"(c), "=&v"(d)
      : "v"(q), "v"(q + 16), "v"(q + 32), "v"(q + 48)
      : "memory");
}

// ---------------------------------------------------------------------------
__global__ __launch_bounds__(256) void conv_f32_to_bf16(const float* __restrict__ in,
                                                        uint4* __restrict__ out, int n16) {
  int i = blockIdx.x * 256 + threadIdx.x;
  const int stride = gridDim.x * 256;
  for (; i < n16; i += stride) {
    float4 a = ((const float4*)in)[2 * i];
    float4 b = ((const float4*)in)[2 * i + 1];
    uint4 o;
    o.x = (unsigned)f2bf(a.x) | ((unsigned)f2bf(a.y) << 16);
    o.y = (unsigned)f2bf(a.z) | ((unsigned)f2bf(a.w) << 16);
    o.z = (unsigned)f2bf(b.x) | ((unsigned)f2bf(b.y) << 16);
    o.w = (unsigned)f2bf(b.z) | ((unsigned)f2bf(b.w) << 16);
    out[i] = o;
  }
}

// ---------------------------------------------------------------------------
__global__ __launch_bounds__(256) void transpose_to_bf16(const float* __restrict__ in,
                                                         unsigned short* __restrict__ out,
                                                         int R, int C) {
  __shared__ unsigned short tile[64][72];
  const int tx = threadIdx.x & 63, ty = threadIdx.x >> 6;
  const int c0 = blockIdx.x * 64, r0 = blockIdx.y * 64;
#pragma unroll
  for (int rr = ty; rr < 64; rr += 4)
    tile[rr][tx] = f2bf(in[(size_t)(r0 + rr) * C + c0 + tx]);
  __syncthreads();
#pragma unroll
  for (int cc = ty; cc < 64; cc += 4)
    out[(size_t)(c0 + cc) * R + r0 + tx] = tile[tx][cc];
}

// ---------------------------------------------------------------------------
// hist init: per group, slot 0 (h0) = 0.0, slots 1..1024 = sentinel.
// Runs EVERY launch (graph replays reuse the buffer).
// ---------------------------------------------------------------------------
__global__ __launch_bounds__(256) void init_hist(uint4* __restrict__ hist4) {
  const unsigned per_g = 1025u * 1024u;          // uint4 per 16KB-slot group region
  const unsigned total = NGROUP * per_g;
  unsigned i = blockIdx.x * 256 + threadIdx.x;
  const unsigned stride = gridDim.x * 256;
  for (; i < total; i += stride) {
    const unsigned w = i % per_g;
    const unsigned v = (w < 1024u) ? 0u : SENT;  // slot 0 = 1024 uint4
    hist4[i] = make_uint4(v, v, v, v);
  }
}

// ---------------------------------------------------------------------------
// Phase 1 GEMM (unchanged, proven): 128x128 tile, BK=64, global_load_lds.
// ---------------------------------------------------------------------------
__global__ __launch_bounds__(256, 1) void gemm_xw(const unsigned short* __restrict__ A,
                                                  const unsigned short* __restrict__ Bt,
                                                  unsigned short* __restrict__ C) {
  __shared__ __align__(16) char Al[128 * 128];
  __shared__ __align__(16) char Bl[128 * 128];
  const int tid = threadIdx.x, lane = tid & 63, wave = tid >> 6;
  const int n0 = blockIdx.x * 128;
  const size_t m0 = (size_t)blockIdx.y * 128;
  const int wm = wave >> 1, wn = wave & 1;
  f32x4 acc[4][4] = {};

  for (int ks = 0; ks < 8; ++ks) {
    const int k0 = ks * 64;
    if (ks) __syncthreads();
#pragma unroll
    for (int p = 0; p < 4; ++p) {
      const int off = p * 4096 + wave * 1024 + lane * 16;
      const int row = off >> 7, kb = off & 127;
      const unsigned short* ga = A + (m0 + row) * 512 + k0 + (kb >> 1);
      const unsigned short* gb = Bt + (size_t)(n0 + row) * 512 + k0 + (kb >> 1);
      __builtin_amdgcn_global_load_lds(
          (const __attribute__((address_space(1))) void*)ga,
          (__attribute__((address_space(3))) void*)(Al + p * 4096 + wave * 1024), 16, 0, 0);
      __builtin_amdgcn_global_load_lds(
          (const __attribute__((address_space(1))) void*)gb,
          (__attribute__((address_space(3))) void*)(Bl + p * 4096 + wave * 1024), 16, 0, 0);
    }
    __syncthreads();
#pragma unroll
    for (int kk = 0; kk < 2; ++kk) {
      const int kb = (kk * 32 + (lane >> 4) * 8) * 2;
      bf16x8 av[4], bv[4];
#pragma unroll
      for (int i = 0; i < 4; ++i)
        av[i] = *(const bf16x8*)(Al + (wm * 64 + i * 16 + (lane & 15)) * 128 + kb);
#pragma unroll
      for (int j = 0; j < 4; ++j)
        bv[j] = *(const bf16x8*)(Bl + (wn * 64 + j * 16 + (lane & 15)) * 128 + kb);
#pragma unroll
      for (int i = 0; i < 4; ++i)
#pragma unroll
        for (int j = 0; j < 4; ++j)
          acc[i][j] = __builtin_amdgcn_mfma_f32_16x16x32_bf16(av[i], bv[j], acc[i][j], 0, 0, 0);
    }
  }
#pragma unroll
  for (int i = 0; i < 4; ++i)
#pragma unroll
    for (int j = 0; j < 4; ++j) {
      const int col = n0 + wn * 64 + j * 16 + (lane & 15);
#pragma unroll
      for (int r = 0; r < 4; ++r) {
        const int row = wm * 64 + i * 16 + (lane >> 4) * 4 + r;
        C[(m0 + row) * (size_t)2048 + col] = f2bf(acc[i][j][r]);
      }
    }
}

// ---------------------------------------------------------------------------
// Phase 2: sequential LSTM. 64 blocks x 256 threads (4 waves).
// group g = bid&3 (rows g*16..+16), bg = bid>>2 owns h-cols [bg*32, +32).
// Wave w owns 8 cols [C0, C0+8), C0 = bg*32 + w*8.
// MFMA: D = mfma(A=U-frag, B=h-frag). A rows r16 = (colpair = r16>>2,
// gate = r16&3); mfma1 covers cols C0+2*cp (even), mfma2 cols C0+2*cp+1.
// D: lane (b = lane&15, q = lane>>4) holds acc1[r] = gate r of (b, C0+2q)
// and acc2[r] = gate r of (b, C0+2q+1) -> elementwise/c-state/publish all
// lane-local. One barrier per step (stage -> read). U frags pinned in VGPRs.
// ---------------------------------------------------------------------------
__global__ __launch_bounds__(256, 1) void lstm_seq(const unsigned* __restrict__ xW,       // bf16 pairs [65536][1024]
                                                   const unsigned short* __restrict__ Ut, // bf16 [2048][512]
                                                   const float* __restrict__ bias,        // [2048]
                                                   float* __restrict__ out,
                                                   unsigned* __restrict__ hist) {
  __shared__ __align__(16) unsigned short hl[2][16 * 512];  // dbuf, 32KB

  const int tid = threadIdx.x, lane = tid & 63, wave = tid >> 6;
  const int g = blockIdx.x & 3;
  const int bg = blockIdx.x >> 2;
  const int C0 = bg * 32 + wave * 8;
  const int bm0 = g * 16;

  // A-side (U-frag load) roles
  const int r16 = lane & 15;            // A row within the 16
  const int gate_a = r16 & 3;           // gate of this A row
  const int cp_a = r16 >> 2;            // col-pair of this A row
  const int kq = lane >> 4;             // k-chunk id (8 elems within ks-slice)
  // D-side (output) roles
  const int b = lane & 15;              // batch row (in group)
  const int q = lane >> 4;              // col-pair id
  const int colA = C0 + 2 * q;          // output cols colA, colA+1
  const int bglob = bm0 + b;

  // ---- one-time: U fragments (2 mfma x 16 ks), pinned resident (128 VGPR) ----
  bf16x8 uf1[16], uf2[16];
  {
    const unsigned short* ua = Ut + (size_t)(gate_a * 512 + C0 + 2 * cp_a) * 512 + kq * 8;
#pragma unroll
    for (int ks = 0; ks < 16; ++ks) {
      uf1[ks] = *(const bf16x8*)(ua + ks * 32);
      uf2[ks] = *(const bf16x8*)(ua + 512 + ks * 32);   // col +1 -> one U row down
      asm volatile("" : "+v"(uf1[ks]));                 // pin: not rematerializable
      asm volatile("" : "+v"(uf2[ks]));
    }
  }

  float biasA[4], biasB[4];
#pragma unroll
  for (int r = 0; r < 4; ++r) {
    biasA[r] = bias[r * 512 + colA];
    biasB[r] = bias[r * 512 + colA + 1];
  }
  float cA = 0.f, cB = 0.f;             // cell state, lane-local

  // h B-frag read (from hl, round-2 swizzle): row = lane&15, k-chunk kq
  const int am = lane & 15;
  const int asw = (am & 7) << 4;
  const int kgb = kq * 16;
  // stage roles (thread tid stages 64B of row tid>>4)
  const int rowb = (tid >> 4) * 1024;
  const int colb = (tid & 15) * 64;
  const int sw = ((tid >> 4) & 7) << 4;

  __syncthreads();

  for (int t = 0; t < T_STEPS; ++t) {
    // ---- xW(t) loads at loop top: drain under the poll's vmcnt(0) ----
    unsigned xwv[4];
    {
      const unsigned* base = xW + (size_t)(bglob * T_STEPS + t) * 1024;
#pragma unroll
      for (int r = 0; r < 4; ++r) xwv[r] = base[r * 256 + (colA >> 1)];
    }
    // ---- poll h_t data (sentinel; single LLC round trip) ----
    uint4 pa, pb, pc, pd;
    {
      const char* hb = (const char*)hist + (size_t)(g * 1025 + t) * 16384 + tid * 64;
      for (;;) {
        ldg_64B_llc(hb, pa, pb, pc, pd);
        const bool bad = (pa.x == SENT) | (pa.y == SENT) | (pa.z == SENT) | (pa.w == SENT) |
                         (pb.x == SENT) | (pb.y == SENT) | (pb.z == SENT) | (pb.w == SENT) |
                         (pc.x == SENT) | (pc.y == SENT) | (pc.z == SENT) | (pc.w == SENT) |
                         (pd.x == SENT) | (pd.y == SENT) | (pd.z == SENT) | (pd.w == SENT);
        if (!bad) break;
      }
    }
    // ---- stage h_t to LDS (swizzled), double-buffered ----
    {
      char* dst = (char*)hl[t & 1];
      *(uint4*)(dst + ((rowb + colb) ^ sw)) = pa;
      *(uint4*)(dst + ((rowb + colb + 16) ^ sw)) = pb;
      *(uint4*)(dst + ((rowb + colb + 32) ^ sw)) = pc;
      *(uint4*)(dst + ((rowb + colb + 48) ^ sw)) = pd;
    }
    __syncthreads();  // the ONLY barrier per step

    // ---- acc init = bias + xW(t) ----
    f32x4 acc1, acc2;
#pragma unroll
    for (int r = 0; r < 4; ++r) {
      acc1[r] = biasA[r] + bf_lo(xwv[r]);
      acc2[r] = biasB[r] + bf_hi(xwv[r]);
    }
    // ---- 32 MFMA: 2 independent chains of 16 (h from LDS, U from VGPRs) ----
    const char* hbase = (const char*)hl[t & 1];
#pragma unroll
    for (int ks = 0; ks < 16; ++ks) {
      const bf16x8 hb8 = *(const bf16x8*)(hbase + ((am * 1024 + ks * 64 + kgb) ^ asw));
      acc1 = __builtin_amdgcn_mfma_f32_16x16x32_bf16(uf1[ks], hb8, acc1, 0, 0, 0);
      acc2 = __builtin_amdgcn_mfma_f32_16x16x32_bf16(uf2[ks], hb8, acc2, 0, 0, 0);
    }

    // ---- lane-local elementwise: 2 cells (b, colA), (b, colA+1) ----
    const float iA = fast_sig(acc1[0]), fA = fast_sig(acc1[1]);
    const float gA = fast_tanh(acc1[2]), oA = fast_sig(acc1[3]);
    cA = fA * cA + iA * gA;
    const float hA = oA * fast_tanh(cA);
    const float iB = fast_sig(acc2[0]), fB = fast_sig(acc2[1]);
    const float gB = fast_tanh(acc2[2]), oB = fast_sig(acc2[3]);
    cB = fB * cB + iB * gB;
    const float hB = oB * fast_tanh(cB);

    // ---- publish h_{t+1} FIRST (one u32, system scope) ----
    const unsigned hp = (unsigned)f2bf(hA) | ((unsigned)f2bf(hB) << 16);
    stg_u32_llc(hist + (size_t)(g * 1025 + t + 1) * HIST_SLOT_U32 + b * 256 + (colA >> 1), hp);
    // ---- fp32 hidden_seq (retires lazily under next poll) ----
    *(float2*)(out + ((size_t)bglob * T_STEPS + t) * HS + colA) = make_float2(hA, hB);
    if (t == T_STEPS - 1) {
      const size_t hs_total = (size_t)64 * T_STEPS * HS;
      *(float2*)(out + hs_total + (size_t)bglob * HS + colA) = make_float2(hA, hB);
      *(float2*)(out + hs_total + 64 * HS + (size_t)bglob * HS + colA) = make_float2(cA, cB);
    }
    // no second barrier: hl double-buffered; next overwrite of hl[t&1] is at
    // t+2's stage, gated by poll(t+2) <- publishes(t+1) <- all waves read hl[t&1]
  }
}

// ---------------------------------------------------------------------------
extern "C" void kernel_launch(void* const* d_in, const int* in_sizes, int n_in,
                              void* d_out, int out_size, void* d_ws, size_t ws_size,
                              hipStream_t stream) {
  const float* x = (const float*)d_in[0];
  const float* W = (const float*)d_in[1];
  const float* U = (const float*)d_in[2];
  const float* bias = (const float*)d_in[3];
  float* out = (float*)d_out;
  char* ws = (char*)d_ws;

  size_t off = 0;
  unsigned short* x_bf = (unsigned short*)(ws + off); off += (size_t)65536 * 512 * 2;        // 64MB
  unsigned short* Wt = (unsigned short*)(ws + off);   off += (size_t)2048 * 512 * 2;         // 2MB
  unsigned short* Ut = (unsigned short*)(ws + off);   off += (size_t)2048 * 512 * 2;         // 2MB
  unsigned* hist = (unsigned*)(ws + off);             off += (size_t)NGROUP * 1025 * 16384;  // 67MB
  unsigned short* xWb = (unsigned short*)(ws + off);  off += (size_t)65536 * 2048 * 2;       // 256MB
  if (ws_size < off) return;

  conv_f32_to_bf16<<<4096, 256, 0, stream>>>(x, (uint4*)x_bf, 33554432 / 8);
  transpose_to_bf16<<<dim3(32, 8), 256, 0, stream>>>(W, Wt, 512, 2048);
  transpose_to_bf16<<<dim3(32, 8), 256, 0, stream>>>(U, Ut, 512, 2048);
  init_hist<<<2048, 256, 0, stream>>>((uint4*)hist);
  gemm_xw<<<dim3(16, 512), 256, 0, stream>>>(x_bf, Wt, xWb);
  lstm_seq<<<64, 256, 0, stream>>>((const unsigned*)xWb, Ut, bias, out, hist);
}